// Round 10
// baseline (201.009 us; speedup 1.0000x reference)
//
#include <hip/hip_runtime.h>
#include <hip/hip_bf16.h>
#include <math.h>

#define N_NODES 50000
#define N_EDGES 640000
#define DIM     128
#define NGRAPH  64
#define DOUT    32
#define CAP     64                      // bucket capacity; mean in-deg 12.8, 64 = ~14 sigma
#define LDSS 136                        // 128 + 8 pad (u16)
#define LDSF 132                        // 128 + 4 pad (f32) for fused pool staging
#define NODES_PER_XCD 6250              // N_NODES/8 ownership ranges

// R9 win: XCD-partitioned fill (group g=blockIdx&7 commits only its node slice)
// -> bucket lines dirty in ONE L2, no cross-XCD false sharing. 176.9us.
#define G_GEMM  782                     // ceil(50000/64)
#define N_FILL  5000                    // 8 groups x 625 chunks (1024 edges/chunk)
#define G_FRONT (G_GEMM + N_FILL)       // 5782

// k_prep grid: 128 weight-cvt + 32 pooled-zero + 49 cnt-zero
#define G_PREP  209

typedef unsigned short u16;
typedef __attribute__((ext_vector_type(8))) short bf16x8;
typedef __attribute__((ext_vector_type(4))) float f32x4;

__device__ __forceinline__ u16 f2bf(float f) {
    unsigned u = __float_as_uint(f);
    return (u16)((u + 0x7FFFu + ((u >> 16) & 1u)) >> 16);
}
__device__ __forceinline__ float bf2f(u16 h) {
    return __uint_as_float(((unsigned)h) << 16);
}
__device__ __forceinline__ short2 cvt2(float x, float y) {
    __hip_bfloat162 h = __float22bfloat162_rn(make_float2(x, y));
    return *(short2*)&h;
}
__device__ __forceinline__ void upk(unsigned u, float& lo, float& hi) {
    lo = __uint_as_float(u << 16);
    hi = __uint_as_float(u & 0xFFFF0000u);
}

// ======== tiny prep: W1/W2 -> swizzled bf16, pooled zero, cnt zero ========
// B frag (16x16x32): lane holds B[k][n], n=lane&15, k=(lane>>4)*8+j  [verified R5-R10]
__global__ __launch_bounds__(256) void k_prep(const float* __restrict__ W1,
                                              const float* __restrict__ W2,
                                              u16* __restrict__ W1s,
                                              u16* __restrict__ W2s,
                                              float* __restrict__ pooled,
                                              int* __restrict__ cnt) {
    int b = blockIdx.x;
    int tid = threadIdx.x;
    if (b < 128) {
        int t = (b & 63) * 256 + tid;       // 0..16383
        int j = t & 7, lane = (t >> 3) & 63, kc = (t >> 9) & 3, nt = t >> 11;
        int k = kc * 32 + (lane >> 4) * 8 + j;
        int n = nt * 16 + (lane & 15);
        if (b < 64) W1s[t] = f2bf(W1[k * 128 + n]);
        else        W2s[t] = f2bf(W2[k * 128 + n]);
    } else if (b < 160) {
        int t = (b - 128) * 256 + tid;
        pooled[t] = 0.f;                    // exactly 8192
    } else {
        int t = (b - 160) * 256 + tid;      // int4 index; 50000/4 = 12500
        if (t < 12500) {
            int4 z = {0, 0, 0, 0};
            *(int4*)(cnt + t * 4) = z;
        }
    }
}

// ======== fused front kernel (ZERO LDS) ========
// branch 1 (b < G_GEMM): MFMA GEMM1  Y(bf16) = Xfp32 @ W1  (UNSCALED — dinv applied at
//   agg1 gather). W1s read from global (L2 broadcast).
// branch 2: XCD-partitioned fill (R9 win, see header comment).
// A frag: A[m=lane&15][k=(lane>>4)*8+j]; C/D: col=lane&15, row=(lane>>4)*4+reg.
__global__ __launch_bounds__(256) void k_front(const float* __restrict__ X,
                                               const int* __restrict__ src,
                                               const int* __restrict__ dst,
                                               int* __restrict__ cnt,
                                               int* __restrict__ bucket,
                                               const u16* __restrict__ Ws,
                                               u16* __restrict__ Y) {
    int b   = blockIdx.x;
    int tid = threadIdx.x;

    if (b < G_GEMM) {
        int wv   = tid >> 6;
        int lane = tid & 63;
        int row0 = b * 64 + wv * 16;
        int m    = lane & 15;
        int quad = lane >> 4;
        int ar = min(row0 + m, N_NODES - 1);
        const float* Arow = X + (size_t)ar * DIM;
        bf16x8 a[4];
#pragma unroll
        for (int kc = 0; kc < 4; ++kc) {
            const float4* p4 = (const float4*)(Arow + kc * 32 + quad * 8);
            float4 p = p4[0], q = p4[1];
            short2 s0 = cvt2(p.x, p.y), s1 = cvt2(p.z, p.w);
            short2 s2 = cvt2(q.x, q.y), s3 = cvt2(q.z, q.w);
            bf16x8 av;
            av[0] = s0.x; av[1] = s0.y; av[2] = s1.x; av[3] = s1.y;
            av[4] = s2.x; av[5] = s2.y; av[6] = s3.x; av[7] = s3.y;
            a[kc] = av;
        }
#pragma unroll
        for (int nt = 0; nt < 8; ++nt) {
            f32x4 acc = {0.f, 0.f, 0.f, 0.f};
#pragma unroll
            for (int kc = 0; kc < 4; ++kc) {
                bf16x8 bb = *(const bf16x8*)(Ws + ((size_t)(nt * 4 + kc) * 64 + lane) * 8);
                acc = __builtin_amdgcn_mfma_f32_16x16x32_bf16(a[kc], bb, acc, 0, 0, 0);
            }
            int col = nt * 16 + m;
#pragma unroll
            for (int r = 0; r < 4; ++r) {
                int rr = row0 + quad * 4 + r;
                if (rr < N_NODES) Y[(size_t)rr * DIM + col] = f2bf(acc[r]);  // unscaled
            }
        }
    } else {
        int bb = b - G_GEMM;
        int g  = b & 7;                      // XCD group (abs blockIdx round-robin)
        int e  = (bb >> 3) * 1024 + tid * 4; // chunk = bb/8
        int4 s4 = *(const int4*)(src + e);
        int4 d4 = *(const int4*)(dst + e);
        if (d4.x / NODES_PER_XCD == g) {
            int p = atomicAdd(&cnt[d4.x], 1);
            bucket[d4.x * CAP + p] = s4.x;
        }
        if (d4.y / NODES_PER_XCD == g) {
            int p = atomicAdd(&cnt[d4.y], 1);
            bucket[d4.y * CAP + p] = s4.y;
        }
        if (d4.z / NODES_PER_XCD == g) {
            int p = atomicAdd(&cnt[d4.z], 1);
            bucket[d4.z * CAP + p] = s4.z;
        }
        if (d4.w / NODES_PER_XCD == g) {
            int p = atomicAdd(&cnt[d4.w], 1);
            bucket[d4.w * CAP + p] = s4.w;
        }
    }
}

// ================= fused agg1 + gemm2 (16 nodes/block; 50000 = 3125*16) =================
// H is UNSCALED h = X@W1; per-edge weight = dinv[src] gathered from L2-hot 200KB cnt,
// self term weighted dinv[i]; output pre-scaled by dinv[i] for layer 2.
// 16 edges/iter (R10): 85% of nodes finish in ONE gather round (was E[max]~2.5 at 8/iter).
__global__ __launch_bounds__(256) void k_agg_gemm(const u16* __restrict__ H,
                                                  const int* __restrict__ bucket,
                                                  const int* __restrict__ cnt,
                                                  const float* __restrict__ bias,
                                                  const u16* __restrict__ Ws,
                                                  u16* __restrict__ Y) {
    __shared__ u16 As[16][LDSS];
    int tid    = threadIdx.x;
    int nloc   = tid >> 4;
    int lane16 = tid & 15;
    int node   = blockIdx.x * 16 + nloc;

    // ---- phase A: quarter-wave aggregate ----
    int deg = cnt[node];
    float dself = rsqrtf((float)(deg + 1));
    int e0 = node * CAP, e1 = e0 + deg;
    const uint4* H4 = (const uint4*)H;
    uint4 sv = H4[(size_t)node * 16 + lane16];
    float a0[8], a1[8] = {}, a2[8] = {}, a3[8] = {};
    {   // self-loop term carries weight dinv[i]
        float lo, hi;
        upk(sv.x, lo, hi); a0[0] = dself * lo; a0[1] = dself * hi;
        upk(sv.y, lo, hi); a0[2] = dself * lo; a0[3] = dself * hi;
        upk(sv.z, lo, hi); a0[4] = dself * lo; a0[5] = dself * hi;
        upk(sv.w, lo, hi); a0[6] = dself * lo; a0[7] = dself * hi;
    }
    // one-ahead prefetch of bucket row (hides idx->gather dependency)
    int4 c0, c1, c2, c3;
    if (e0 < e1) {
        c0 = *(const int4*)(bucket + e0);      c1 = *(const int4*)(bucket + e0 + 4);
        c2 = *(const int4*)(bucket + e0 + 8);  c3 = *(const int4*)(bucket + e0 + 12);
    }
    for (int e = e0; e < e1; e += 16) {
        int4 p0 = c0, p1 = c1, p2 = c2, p3 = c3;
        if (e + 16 < e1) {
            c0 = *(const int4*)(bucket + e + 16); c1 = *(const int4*)(bucket + e + 20);
            c2 = *(const int4*)(bucket + e + 24); c3 = *(const int4*)(bucket + e + 28);
        }
        int   idx[16];
        float w[16];
        uint4 v[16];
        int   cd[16];
        idx[0]  = p0.x; idx[1]  = p0.y; idx[2]  = p0.z; idx[3]  = p0.w;
        idx[4]  = p1.x; idx[5]  = p1.y; idx[6]  = p1.z; idx[7]  = p1.w;
        idx[8]  = p2.x; idx[9]  = p2.y; idx[10] = p2.z; idx[11] = p2.w;
        idx[12] = p3.x; idx[13] = p3.y; idx[14] = p3.z; idx[15] = p3.w;
#pragma unroll
        for (int u = 0; u < 16; ++u) {
            bool in = (e + u) < e1;          // slots >= deg hold garbage: sanitize
            w[u]   = in ? 1.f : 0.f;
            idx[u] = in ? idx[u] : 0;        // masked slots hit node0 row (L2-hot)
        }
#pragma unroll
        for (int u = 0; u < 16; ++u) cd[u] = cnt[idx[u]];         // L2-hot 200KB
#pragma unroll
        for (int u = 0; u < 16; ++u) v[u] = H4[(size_t)idx[u] * 16 + lane16];
#pragma unroll
        for (int u = 0; u < 16; ++u) w[u] *= rsqrtf((float)(cd[u] + 1));  // dinv[src]
#pragma unroll
        for (int u = 0; u < 16; ++u) {
            float* a = (u & 3) == 0 ? a0 : (u & 3) == 1 ? a1 : (u & 3) == 2 ? a2 : a3;
            float lo, hi;
            upk(v[u].x, lo, hi); a[0] = fmaf(w[u], lo, a[0]); a[1] = fmaf(w[u], hi, a[1]);
            upk(v[u].y, lo, hi); a[2] = fmaf(w[u], lo, a[2]); a[3] = fmaf(w[u], hi, a[3]);
            upk(v[u].z, lo, hi); a[4] = fmaf(w[u], lo, a[4]); a[5] = fmaf(w[u], hi, a[5]);
            upk(v[u].w, lo, hi); a[6] = fmaf(w[u], lo, a[6]); a[7] = fmaf(w[u], hi, a[7]);
        }
    }
    {
        float di = dself;
        const float4* b4 = (const float4*)bias;
        float4 blo = b4[lane16 * 2], bhi = b4[lane16 * 2 + 1];
        float r0 = fmaxf(di * (a0[0] + a1[0] + a2[0] + a3[0]) + blo.x, 0.f);
        float r1 = fmaxf(di * (a0[1] + a1[1] + a2[1] + a3[1]) + blo.y, 0.f);
        float r2 = fmaxf(di * (a0[2] + a1[2] + a2[2] + a3[2]) + blo.z, 0.f);
        float r3 = fmaxf(di * (a0[3] + a1[3] + a2[3] + a3[3]) + blo.w, 0.f);
        float r4 = fmaxf(di * (a0[4] + a1[4] + a2[4] + a3[4]) + bhi.x, 0.f);
        float r5 = fmaxf(di * (a0[5] + a1[5] + a2[5] + a3[5]) + bhi.y, 0.f);
        float r6 = fmaxf(di * (a0[6] + a1[6] + a2[6] + a3[6]) + bhi.z, 0.f);
        float r7 = fmaxf(di * (a0[7] + a1[7] + a2[7] + a3[7]) + bhi.w, 0.f);
        short2 s0 = cvt2(r0, r1), s1 = cvt2(r2, r3), s2 = cvt2(r4, r5), s3 = cvt2(r6, r7);
        uint4 o;
        o.x = *(unsigned*)&s0; o.y = *(unsigned*)&s1;
        o.z = *(unsigned*)&s2; o.w = *(unsigned*)&s3;
        *(uint4*)(&As[nloc][lane16 * 8]) = o;
    }
    __syncthreads();

    // ---- phase B: 16x128 @ 128x128 MFMA; wave wv owns cols wv*32..wv*32+31 ----
    // output pre-scaled by dinv[row] (cnt is complete here)
    int wv   = tid >> 6;
    int lane = tid & 63;
    int m    = lane & 15;
    int quad = lane >> 4;
    bf16x8 a[4];
#pragma unroll
    for (int kc = 0; kc < 4; ++kc)
        a[kc] = *(const bf16x8*)(&As[m][kc * 32 + quad * 8]);
    float di[4];
#pragma unroll
    for (int r = 0; r < 4; ++r)
        di[r] = rsqrtf((float)(cnt[blockIdx.x * 16 + quad * 4 + r] + 1));
#pragma unroll
    for (int i = 0; i < 2; ++i) {
        int nt = wv * 2 + i;
        f32x4 acc = {0.f, 0.f, 0.f, 0.f};
#pragma unroll
        for (int kc = 0; kc < 4; ++kc) {
            bf16x8 b = *(const bf16x8*)(Ws + ((size_t)(nt * 4 + kc) * 64 + lane) * 8);
            acc = __builtin_amdgcn_mfma_f32_16x16x32_bf16(a[kc], b, acc, 0, 0, 0);
        }
        int col = nt * 16 + m;
#pragma unroll
        for (int r = 0; r < 4; ++r) {
            int rr = blockIdx.x * 16 + quad * 4 + r;
            Y[(size_t)rr * DIM + col] = f2bf(acc[r] * di[r]);
        }
    }
}

// ================= agg layer 2 + fused global-add-pool =================
// H2 is pre-scaled by dinv (baked in at agg_gemm phase B), so gather is unweighted.
// 16 edges/iter (R10), same rationale as agg_gemm.
__global__ __launch_bounds__(256) void k_agg_pool(const u16* __restrict__ H,
                                                  const int* __restrict__ bucket,
                                                  const int* __restrict__ cnt,
                                                  const float* __restrict__ bias,
                                                  const int* __restrict__ batch,
                                                  float* __restrict__ pooled) {
    __shared__ float As[16][LDSF];
    __shared__ int bs[16];
    int tid  = threadIdx.x;
    int nloc = tid >> 4;
    int lane = tid & 15;
    int node = blockIdx.x * 16 + nloc;   // grid exact: 3125*16 == 50000

    int deg = cnt[node];
    int e0 = node * CAP, e1 = e0 + deg;
    const uint4* H4 = (const uint4*)H;
    uint4 sv = H4[(size_t)node * 16 + lane];
    float a0[8], a1[8] = {}, a2[8] = {}, a3[8] = {};
    upk(sv.x, a0[0], a0[1]); upk(sv.y, a0[2], a0[3]);
    upk(sv.z, a0[4], a0[5]); upk(sv.w, a0[6], a0[7]);
    int4 c0, c1, c2, c3;
    if (e0 < e1) {
        c0 = *(const int4*)(bucket + e0);      c1 = *(const int4*)(bucket + e0 + 4);
        c2 = *(const int4*)(bucket + e0 + 8);  c3 = *(const int4*)(bucket + e0 + 12);
    }
    for (int e = e0; e < e1; e += 16) {
        int4 p0 = c0, p1 = c1, p2 = c2, p3 = c3;
        if (e + 16 < e1) {
            c0 = *(const int4*)(bucket + e + 16); c1 = *(const int4*)(bucket + e + 20);
            c2 = *(const int4*)(bucket + e + 24); c3 = *(const int4*)(bucket + e + 28);
        }
        int   idx[16];
        float w[16];
        uint4 v[16];
        idx[0]  = p0.x; idx[1]  = p0.y; idx[2]  = p0.z; idx[3]  = p0.w;
        idx[4]  = p1.x; idx[5]  = p1.y; idx[6]  = p1.z; idx[7]  = p1.w;
        idx[8]  = p2.x; idx[9]  = p2.y; idx[10] = p2.z; idx[11] = p2.w;
        idx[12] = p3.x; idx[13] = p3.y; idx[14] = p3.z; idx[15] = p3.w;
#pragma unroll
        for (int u = 0; u < 16; ++u) {
            bool in = (e + u) < e1;
            w[u]   = in ? 1.f : 0.f;
            idx[u] = in ? idx[u] : 0;
        }
#pragma unroll
        for (int u = 0; u < 16; ++u) v[u] = H4[(size_t)idx[u] * 16 + lane];
#pragma unroll
        for (int u = 0; u < 16; ++u) {
            float* a = (u & 3) == 0 ? a0 : (u & 3) == 1 ? a1 : (u & 3) == 2 ? a2 : a3;
            float lo, hi;
            upk(v[u].x, lo, hi); a[0] = fmaf(w[u], lo, a[0]); a[1] = fmaf(w[u], hi, a[1]);
            upk(v[u].y, lo, hi); a[2] = fmaf(w[u], lo, a[2]); a[3] = fmaf(w[u], hi, a[3]);
            upk(v[u].z, lo, hi); a[4] = fmaf(w[u], lo, a[4]); a[5] = fmaf(w[u], hi, a[5]);
            upk(v[u].w, lo, hi); a[6] = fmaf(w[u], lo, a[6]); a[7] = fmaf(w[u], hi, a[7]);
        }
    }
    {
        float di = rsqrtf((float)(deg + 1));
        const float4* b4 = (const float4*)bias;
        float4 blo = b4[lane * 2], bhi = b4[lane * 2 + 1];
        float4 olo, ohi;
        olo.x = fmaxf(di * (a0[0] + a1[0] + a2[0] + a3[0]) + blo.x, 0.f);
        olo.y = fmaxf(di * (a0[1] + a1[1] + a2[1] + a3[1]) + blo.y, 0.f);
        olo.z = fmaxf(di * (a0[2] + a1[2] + a2[2] + a3[2]) + blo.z, 0.f);
        olo.w = fmaxf(di * (a0[3] + a1[3] + a2[3] + a3[3]) + blo.w, 0.f);
        ohi.x = fmaxf(di * (a0[4] + a1[4] + a2[4] + a3[4]) + bhi.x, 0.f);
        ohi.y = fmaxf(di * (a0[5] + a1[5] + a2[5] + a3[5]) + bhi.y, 0.f);
        ohi.z = fmaxf(di * (a0[6] + a1[6] + a2[6] + a3[6]) + bhi.z, 0.f);
        ohi.w = fmaxf(di * (a0[7] + a1[7] + a2[7] + a3[7]) + bhi.w, 0.f);
        *(float4*)(&As[nloc][lane * 8])     = olo;
        *(float4*)(&As[nloc][lane * 8 + 4]) = ohi;
    }
    if (lane == 0) bs[nloc] = batch[node];
    __syncthreads();

    // ---- pooling: 128 threads, one dim each; run-length over sorted batch ids ----
    if (tid < 128) {
        float acc = 0.f;
        int cb = bs[0];
#pragma unroll
        for (int n = 0; n < 16; ++n) {
            int b = bs[n];
            if (b != cb) {
                atomicAdd(&pooled[cb * DIM + tid], acc);
                acc = 0.f; cb = b;
            }
            acc += As[n][tid];
        }
        atomicAdd(&pooled[cb * DIM + tid], acc);
    }
}

// ---- head: logits = pooled @ Wh + bh ; log_softmax per graph ----
__global__ __launch_bounds__(64) void k_head(const float* __restrict__ pooled,
                                             const float* __restrict__ Wh,
                                             const float* __restrict__ bh,
                                             float* __restrict__ out) {
    int g = blockIdx.x;
    int lane = threadIdx.x;
    int c = lane & 31;
    const float* p = pooled + g * DIM;
    float lg = bh[c];
#pragma unroll 8
    for (int k = 0; k < DIM; ++k) lg = fmaf(p[k], Wh[k * DOUT + c], lg);
    float m = lg;
    for (int off = 16; off >= 1; off >>= 1) m = fmaxf(m, __shfl_xor(m, off, 32));
    float ex = expf(lg - m);
    float s = ex;
    for (int off = 16; off >= 1; off >>= 1) s += __shfl_xor(s, off, 32);
    if (lane < 32) out[g * DOUT + c] = lg - m - logf(s);
}

extern "C" void kernel_launch(void* const* d_in, const int* in_sizes, int n_in,
                              void* d_out, int out_size, void* d_ws, size_t ws_size,
                              hipStream_t stream) {
    const float* x     = (const float*)d_in[0];
    const int*   ei    = (const int*)d_in[1];
    const int*   batch = (const int*)d_in[2];
    const float* W1    = (const float*)d_in[3];
    const float* b1    = (const float*)d_in[4];
    const float* W2    = (const float*)d_in[5];
    const float* b2    = (const float*)d_in[6];
    const float* Wh    = (const float*)d_in[7];
    const float* bh    = (const float*)d_in[8];
    float* out = (float*)d_out;
    const int* src = ei;
    const int* dst = ei + N_EDGES;

    char* ws = (char*)d_ws;
    size_t off = 0;
    auto alloc = [&](size_t bytes) {
        void* p = ws + off;
        off += (bytes + 255) & ~(size_t)255;
        return p;
    };
    u16*   bufA   = (u16*) alloc((size_t)N_NODES * DIM * 2);        // 12.8 MB bf16
    u16*   bufB   = (u16*) alloc((size_t)N_NODES * DIM * 2);        // 12.8 MB bf16
    int*   cnt    = (int*) alloc((size_t)N_NODES * 4);              // 200 KB packed
    int*   bucket = (int*) alloc((size_t)N_NODES * CAP * 4);        // 12.8 MB
    u16*   W1s    = (u16*) alloc((size_t)DIM * DIM * 2);
    u16*   W2s    = (u16*) alloc((size_t)DIM * DIM * 2);
    float* pooled = (float*)alloc((size_t)NGRAPH * DIM * 4);
    (void)ws_size; (void)in_sizes; (void)n_in; (void)out_size;

    k_prep    <<<G_PREP, 256, 0, stream>>>(W1, W2, W1s, W2s, pooled, cnt);
    k_front   <<<G_FRONT, 256, 0, stream>>>(x, src, dst, cnt, bucket, W1s, bufA);
    k_agg_gemm<<<N_NODES / 16, 256, 0, stream>>>(bufA, bucket, cnt, b1, W2s, bufB);
    k_agg_pool<<<N_NODES / 16, 256, 0, stream>>>(bufB, bucket, cnt, b2, batch, pooled);

    k_head<<<NGRAPH, 64, 0, stream>>>(pooled, Wh, bh, out);
}

// Round 11
// 175.974 us; speedup vs baseline: 1.1423x; 1.1423x over previous
//
#include <hip/hip_runtime.h>
#include <hip/hip_bf16.h>
#include <math.h>

#define N_NODES 50000
#define N_EDGES 640000
#define DIM     128
#define NGRAPH  64
#define DOUT    32
#define CAP     64                      // bucket capacity; mean in-deg 12.8, 64 = ~14 sigma
#define LDSS 136                        // 128 + 8 pad (u16)
#define LDSF 132                        // 128 + 4 pad (f32) for fused pool staging

// R9 win: XCD-partitioned fill -> bucket/cnt lines dirty in ONE L2 (no cross-XCD
// false sharing). R10 lesson: 16 edges/iter raised VGPR to 104, occupancy 18%,
// REGRESSED -> reverted to 8/iter. R11: ownership = (d>>4)&7 (16-node groups):
// same single-XCD invariant (bucket row=4 lines, cnt line=16 counters, both within
// one group), no integer division, agg block b auto-aligned (nodes 16b.. -> group b&7).
#define G_GEMM  782                     // ceil(50000/64)
#define N_FILL  5000                    // 8 groups x 625 chunks (1024 edges/chunk)
#define G_FRONT (G_GEMM + N_FILL)       // 5782

// k_prep grid: 128 weight-cvt + 32 pooled-zero + 49 cnt-zero
#define G_PREP  209

typedef unsigned short u16;
typedef __attribute__((ext_vector_type(8))) short bf16x8;
typedef __attribute__((ext_vector_type(4))) float f32x4;

__device__ __forceinline__ u16 f2bf(float f) {
    unsigned u = __float_as_uint(f);
    return (u16)((u + 0x7FFFu + ((u >> 16) & 1u)) >> 16);
}
__device__ __forceinline__ float bf2f(u16 h) {
    return __uint_as_float(((unsigned)h) << 16);
}
__device__ __forceinline__ short2 cvt2(float x, float y) {
    __hip_bfloat162 h = __float22bfloat162_rn(make_float2(x, y));
    return *(short2*)&h;
}
__device__ __forceinline__ void upk(unsigned u, float& lo, float& hi) {
    lo = __uint_as_float(u << 16);
    hi = __uint_as_float(u & 0xFFFF0000u);
}

// ======== tiny prep: W1/W2 -> swizzled bf16, pooled zero, cnt zero ========
// B frag (16x16x32): lane holds B[k][n], n=lane&15, k=(lane>>4)*8+j  [verified R5-R10]
__global__ __launch_bounds__(256) void k_prep(const float* __restrict__ W1,
                                              const float* __restrict__ W2,
                                              u16* __restrict__ W1s,
                                              u16* __restrict__ W2s,
                                              float* __restrict__ pooled,
                                              int* __restrict__ cnt) {
    int b = blockIdx.x;
    int tid = threadIdx.x;
    if (b < 128) {
        int t = (b & 63) * 256 + tid;       // 0..16383
        int j = t & 7, lane = (t >> 3) & 63, kc = (t >> 9) & 3, nt = t >> 11;
        int k = kc * 32 + (lane >> 4) * 8 + j;
        int n = nt * 16 + (lane & 15);
        if (b < 64) W1s[t] = f2bf(W1[k * 128 + n]);
        else        W2s[t] = f2bf(W2[k * 128 + n]);
    } else if (b < 160) {
        int t = (b - 128) * 256 + tid;
        pooled[t] = 0.f;                    // exactly 8192
    } else {
        int t = (b - 160) * 256 + tid;      // int4 index; 50000/4 = 12500
        if (t < 12500) {
            int4 z = {0, 0, 0, 0};
            *(int4*)(cnt + t * 4) = z;
        }
    }
}

// ======== fused front kernel (ZERO LDS) ========
// branch 1 (b < G_GEMM): MFMA GEMM1  Y(bf16) = Xfp32 @ W1  (UNSCALED — dinv applied at
//   agg1 gather). W1s read from global (L2 broadcast).
// branch 2: XCD-partitioned fill, group g=b&7 commits only edges with (dst>>4)&7==g.
// A frag: A[m=lane&15][k=(lane>>4)*8+j]; C/D: col=lane&15, row=(lane>>4)*4+reg.
__global__ __launch_bounds__(256) void k_front(const float* __restrict__ X,
                                               const int* __restrict__ src,
                                               const int* __restrict__ dst,
                                               int* __restrict__ cnt,
                                               int* __restrict__ bucket,
                                               const u16* __restrict__ Ws,
                                               u16* __restrict__ Y) {
    int b   = blockIdx.x;
    int tid = threadIdx.x;

    if (b < G_GEMM) {
        int wv   = tid >> 6;
        int lane = tid & 63;
        int row0 = b * 64 + wv * 16;
        int m    = lane & 15;
        int quad = lane >> 4;
        int ar = min(row0 + m, N_NODES - 1);
        const float* Arow = X + (size_t)ar * DIM;
        bf16x8 a[4];
#pragma unroll
        for (int kc = 0; kc < 4; ++kc) {
            const float4* p4 = (const float4*)(Arow + kc * 32 + quad * 8);
            float4 p = p4[0], q = p4[1];
            short2 s0 = cvt2(p.x, p.y), s1 = cvt2(p.z, p.w);
            short2 s2 = cvt2(q.x, q.y), s3 = cvt2(q.z, q.w);
            bf16x8 av;
            av[0] = s0.x; av[1] = s0.y; av[2] = s1.x; av[3] = s1.y;
            av[4] = s2.x; av[5] = s2.y; av[6] = s3.x; av[7] = s3.y;
            a[kc] = av;
        }
#pragma unroll
        for (int nt = 0; nt < 8; ++nt) {
            f32x4 acc = {0.f, 0.f, 0.f, 0.f};
#pragma unroll
            for (int kc = 0; kc < 4; ++kc) {
                bf16x8 bb = *(const bf16x8*)(Ws + ((size_t)(nt * 4 + kc) * 64 + lane) * 8);
                acc = __builtin_amdgcn_mfma_f32_16x16x32_bf16(a[kc], bb, acc, 0, 0, 0);
            }
            int col = nt * 16 + m;
#pragma unroll
            for (int r = 0; r < 4; ++r) {
                int rr = row0 + quad * 4 + r;
                if (rr < N_NODES) Y[(size_t)rr * DIM + col] = f2bf(acc[r]);  // unscaled
            }
        }
    } else {
        int bb = b - G_GEMM;
        int g  = b & 7;                      // XCD group (abs blockIdx round-robin)
        int e  = (bb >> 3) * 1024 + tid * 4; // chunk = bb/8
        int4 s4 = *(const int4*)(src + e);
        int4 d4 = *(const int4*)(dst + e);
        if (((d4.x >> 4) & 7) == g) {
            int p = atomicAdd(&cnt[d4.x], 1);
            bucket[d4.x * CAP + p] = s4.x;
        }
        if (((d4.y >> 4) & 7) == g) {
            int p = atomicAdd(&cnt[d4.y], 1);
            bucket[d4.y * CAP + p] = s4.y;
        }
        if (((d4.z >> 4) & 7) == g) {
            int p = atomicAdd(&cnt[d4.z], 1);
            bucket[d4.z * CAP + p] = s4.z;
        }
        if (((d4.w >> 4) & 7) == g) {
            int p = atomicAdd(&cnt[d4.w], 1);
            bucket[d4.w * CAP + p] = s4.w;
        }
    }
}

// ================= fused agg1 + gemm2 (16 nodes/block; 50000 = 3125*16) =================
// H is UNSCALED h = X@W1; per-edge weight = dinv[src] gathered from L2-hot 200KB cnt,
// self term weighted dinv[i]; output pre-scaled by dinv[i] for layer 2.
// 8 edges/iter (R10 lesson: 16/iter -> VGPR 104, occupancy 18%, regression).
__global__ __launch_bounds__(256) void k_agg_gemm(const u16* __restrict__ H,
                                                  const int* __restrict__ bucket,
                                                  const int* __restrict__ cnt,
                                                  const float* __restrict__ bias,
                                                  const u16* __restrict__ Ws,
                                                  u16* __restrict__ Y) {
    __shared__ u16 As[16][LDSS];
    int tid    = threadIdx.x;
    int nloc   = tid >> 4;
    int lane16 = tid & 15;
    int node   = blockIdx.x * 16 + nloc;

    // ---- phase A: quarter-wave aggregate ----
    int deg = cnt[node];
    float dself = rsqrtf((float)(deg + 1));
    int e0 = node * CAP, e1 = e0 + deg;
    const uint4* H4 = (const uint4*)H;
    uint4 sv = H4[(size_t)node * 16 + lane16];
    float a0[8], a1[8] = {}, a2[8] = {}, a3[8] = {};
    {   // self-loop term carries weight dinv[i]
        float lo, hi;
        upk(sv.x, lo, hi); a0[0] = dself * lo; a0[1] = dself * hi;
        upk(sv.y, lo, hi); a0[2] = dself * lo; a0[3] = dself * hi;
        upk(sv.z, lo, hi); a0[4] = dself * lo; a0[5] = dself * hi;
        upk(sv.w, lo, hi); a0[6] = dself * lo; a0[7] = dself * hi;
    }
    // one-ahead prefetch of bucket row (hides idx->gather dependency)
    int4 c0, c1;
    if (e0 < e1) { c0 = *(const int4*)(bucket + e0); c1 = *(const int4*)(bucket + e0 + 4); }
    for (int e = e0; e < e1; e += 8) {
        int4 p0 = c0, p1 = c1;
        if (e + 8 < e1) {
            c0 = *(const int4*)(bucket + e + 8);
            c1 = *(const int4*)(bucket + e + 12);
        }
        int   idx[8];
        float w[8];
        uint4 v[8];
        int   cd[8];
        idx[0] = p0.x; idx[1] = p0.y; idx[2] = p0.z; idx[3] = p0.w;
        idx[4] = p1.x; idx[5] = p1.y; idx[6] = p1.z; idx[7] = p1.w;
#pragma unroll
        for (int u = 0; u < 8; ++u) {
            bool in = (e + u) < e1;          // slots >= deg hold garbage: sanitize
            w[u]   = in ? 1.f : 0.f;
            idx[u] = in ? idx[u] : 0;
        }
#pragma unroll
        for (int u = 0; u < 8; ++u) cd[u] = cnt[idx[u]];          // L2-hot 200KB
#pragma unroll
        for (int u = 0; u < 8; ++u) v[u] = H4[(size_t)idx[u] * 16 + lane16];
#pragma unroll
        for (int u = 0; u < 8; ++u) w[u] *= rsqrtf((float)(cd[u] + 1));  // dinv[src]
#pragma unroll
        for (int u = 0; u < 8; ++u) {
            float* a = (u & 3) == 0 ? a0 : (u & 3) == 1 ? a1 : (u & 3) == 2 ? a2 : a3;
            float lo, hi;
            upk(v[u].x, lo, hi); a[0] = fmaf(w[u], lo, a[0]); a[1] = fmaf(w[u], hi, a[1]);
            upk(v[u].y, lo, hi); a[2] = fmaf(w[u], lo, a[2]); a[3] = fmaf(w[u], hi, a[3]);
            upk(v[u].z, lo, hi); a[4] = fmaf(w[u], lo, a[4]); a[5] = fmaf(w[u], hi, a[5]);
            upk(v[u].w, lo, hi); a[6] = fmaf(w[u], lo, a[6]); a[7] = fmaf(w[u], hi, a[7]);
        }
    }
    {
        float di = dself;
        const float4* b4 = (const float4*)bias;
        float4 blo = b4[lane16 * 2], bhi = b4[lane16 * 2 + 1];
        float r0 = fmaxf(di * (a0[0] + a1[0] + a2[0] + a3[0]) + blo.x, 0.f);
        float r1 = fmaxf(di * (a0[1] + a1[1] + a2[1] + a3[1]) + blo.y, 0.f);
        float r2 = fmaxf(di * (a0[2] + a1[2] + a2[2] + a3[2]) + blo.z, 0.f);
        float r3 = fmaxf(di * (a0[3] + a1[3] + a2[3] + a3[3]) + blo.w, 0.f);
        float r4 = fmaxf(di * (a0[4] + a1[4] + a2[4] + a3[4]) + bhi.x, 0.f);
        float r5 = fmaxf(di * (a0[5] + a1[5] + a2[5] + a3[5]) + bhi.y, 0.f);
        float r6 = fmaxf(di * (a0[6] + a1[6] + a2[6] + a3[6]) + bhi.z, 0.f);
        float r7 = fmaxf(di * (a0[7] + a1[7] + a2[7] + a3[7]) + bhi.w, 0.f);
        short2 s0 = cvt2(r0, r1), s1 = cvt2(r2, r3), s2 = cvt2(r4, r5), s3 = cvt2(r6, r7);
        uint4 o;
        o.x = *(unsigned*)&s0; o.y = *(unsigned*)&s1;
        o.z = *(unsigned*)&s2; o.w = *(unsigned*)&s3;
        *(uint4*)(&As[nloc][lane16 * 8]) = o;
    }
    __syncthreads();

    // ---- phase B: 16x128 @ 128x128 MFMA; wave wv owns cols wv*32..wv*32+31 ----
    // output pre-scaled by dinv[row] (cnt is complete here)
    int wv   = tid >> 6;
    int lane = tid & 63;
    int m    = lane & 15;
    int quad = lane >> 4;
    bf16x8 a[4];
#pragma unroll
    for (int kc = 0; kc < 4; ++kc)
        a[kc] = *(const bf16x8*)(&As[m][kc * 32 + quad * 8]);
    float di[4];
#pragma unroll
    for (int r = 0; r < 4; ++r)
        di[r] = rsqrtf((float)(cnt[blockIdx.x * 16 + quad * 4 + r] + 1));
#pragma unroll
    for (int i = 0; i < 2; ++i) {
        int nt = wv * 2 + i;
        f32x4 acc = {0.f, 0.f, 0.f, 0.f};
#pragma unroll
        for (int kc = 0; kc < 4; ++kc) {
            bf16x8 b = *(const bf16x8*)(Ws + ((size_t)(nt * 4 + kc) * 64 + lane) * 8);
            acc = __builtin_amdgcn_mfma_f32_16x16x32_bf16(a[kc], b, acc, 0, 0, 0);
        }
        int col = nt * 16 + m;
#pragma unroll
        for (int r = 0; r < 4; ++r) {
            int rr = blockIdx.x * 16 + quad * 4 + r;
            Y[(size_t)rr * DIM + col] = f2bf(acc[r] * di[r]);
        }
    }
}

// ================= agg layer 2 + fused global-add-pool =================
// H2 is pre-scaled by dinv (baked in at agg_gemm phase B), so gather is unweighted.
// 8 edges/iter (R10 lesson).
__global__ __launch_bounds__(256) void k_agg_pool(const u16* __restrict__ H,
                                                  const int* __restrict__ bucket,
                                                  const int* __restrict__ cnt,
                                                  const float* __restrict__ bias,
                                                  const int* __restrict__ batch,
                                                  float* __restrict__ pooled) {
    __shared__ float As[16][LDSF];
    __shared__ int bs[16];
    int tid  = threadIdx.x;
    int nloc = tid >> 4;
    int lane = tid & 15;
    int node = blockIdx.x * 16 + nloc;   // grid exact: 3125*16 == 50000

    int deg = cnt[node];
    int e0 = node * CAP, e1 = e0 + deg;
    const uint4* H4 = (const uint4*)H;
    uint4 sv = H4[(size_t)node * 16 + lane];
    float a0[8], a1[8] = {}, a2[8] = {}, a3[8] = {};
    upk(sv.x, a0[0], a0[1]); upk(sv.y, a0[2], a0[3]);
    upk(sv.z, a0[4], a0[5]); upk(sv.w, a0[6], a0[7]);
    int4 c0, c1;
    if (e0 < e1) { c0 = *(const int4*)(bucket + e0); c1 = *(const int4*)(bucket + e0 + 4); }
    for (int e = e0; e < e1; e += 8) {
        int4 p0 = c0, p1 = c1;
        if (e + 8 < e1) {
            c0 = *(const int4*)(bucket + e + 8);
            c1 = *(const int4*)(bucket + e + 12);
        }
        int   idx[8];
        float w[8];
        uint4 v[8];
        idx[0] = p0.x; idx[1] = p0.y; idx[2] = p0.z; idx[3] = p0.w;
        idx[4] = p1.x; idx[5] = p1.y; idx[6] = p1.z; idx[7] = p1.w;
#pragma unroll
        for (int u = 0; u < 8; ++u) {
            bool in = (e + u) < e1;
            w[u]   = in ? 1.f : 0.f;
            idx[u] = in ? idx[u] : 0;
        }
#pragma unroll
        for (int u = 0; u < 8; ++u) v[u] = H4[(size_t)idx[u] * 16 + lane];
#pragma unroll
        for (int u = 0; u < 8; ++u) {
            float* a = (u & 3) == 0 ? a0 : (u & 3) == 1 ? a1 : (u & 3) == 2 ? a2 : a3;
            float lo, hi;
            upk(v[u].x, lo, hi); a[0] = fmaf(w[u], lo, a[0]); a[1] = fmaf(w[u], hi, a[1]);
            upk(v[u].y, lo, hi); a[2] = fmaf(w[u], lo, a[2]); a[3] = fmaf(w[u], hi, a[3]);
            upk(v[u].z, lo, hi); a[4] = fmaf(w[u], lo, a[4]); a[5] = fmaf(w[u], hi, a[5]);
            upk(v[u].w, lo, hi); a[6] = fmaf(w[u], lo, a[6]); a[7] = fmaf(w[u], hi, a[7]);
        }
    }
    {
        float di = rsqrtf((float)(deg + 1));
        const float4* b4 = (const float4*)bias;
        float4 blo = b4[lane * 2], bhi = b4[lane * 2 + 1];
        float4 olo, ohi;
        olo.x = fmaxf(di * (a0[0] + a1[0] + a2[0] + a3[0]) + blo.x, 0.f);
        olo.y = fmaxf(di * (a0[1] + a1[1] + a2[1] + a3[1]) + blo.y, 0.f);
        olo.z = fmaxf(di * (a0[2] + a1[2] + a2[2] + a3[2]) + blo.z, 0.f);
        olo.w = fmaxf(di * (a0[3] + a1[3] + a2[3] + a3[3]) + blo.w, 0.f);
        ohi.x = fmaxf(di * (a0[4] + a1[4] + a2[4] + a3[4]) + bhi.x, 0.f);
        ohi.y = fmaxf(di * (a0[5] + a1[5] + a2[5] + a3[5]) + bhi.y, 0.f);
        ohi.z = fmaxf(di * (a0[6] + a1[6] + a2[6] + a3[6]) + bhi.z, 0.f);
        ohi.w = fmaxf(di * (a0[7] + a1[7] + a2[7] + a3[7]) + bhi.w, 0.f);
        *(float4*)(&As[nloc][lane * 8])     = olo;
        *(float4*)(&As[nloc][lane * 8 + 4]) = ohi;
    }
    if (lane == 0) bs[nloc] = batch[node];
    __syncthreads();

    // ---- pooling: 128 threads, one dim each; run-length over sorted batch ids ----
    if (tid < 128) {
        float acc = 0.f;
        int cb = bs[0];
#pragma unroll
        for (int n = 0; n < 16; ++n) {
            int b = bs[n];
            if (b != cb) {
                atomicAdd(&pooled[cb * DIM + tid], acc);
                acc = 0.f; cb = b;
            }
            acc += As[n][tid];
        }
        atomicAdd(&pooled[cb * DIM + tid], acc);
    }
}

// ---- head: logits = pooled @ Wh + bh ; log_softmax per graph ----
__global__ __launch_bounds__(64) void k_head(const float* __restrict__ pooled,
                                             const float* __restrict__ Wh,
                                             const float* __restrict__ bh,
                                             float* __restrict__ out) {
    int g = blockIdx.x;
    int lane = threadIdx.x;
    int c = lane & 31;
    const float* p = pooled + g * DIM;
    float lg = bh[c];
#pragma unroll 8
    for (int k = 0; k < DIM; ++k) lg = fmaf(p[k], Wh[k * DOUT + c], lg);
    float m = lg;
    for (int off = 16; off >= 1; off >>= 1) m = fmaxf(m, __shfl_xor(m, off, 32));
    float ex = expf(lg - m);
    float s = ex;
    for (int off = 16; off >= 1; off >>= 1) s += __shfl_xor(s, off, 32);
    if (lane < 32) out[g * DOUT + c] = lg - m - logf(s);
}

extern "C" void kernel_launch(void* const* d_in, const int* in_sizes, int n_in,
                              void* d_out, int out_size, void* d_ws, size_t ws_size,
                              hipStream_t stream) {
    const float* x     = (const float*)d_in[0];
    const int*   ei    = (const int*)d_in[1];
    const int*   batch = (const int*)d_in[2];
    const float* W1    = (const float*)d_in[3];
    const float* b1    = (const float*)d_in[4];
    const float* W2    = (const float*)d_in[5];
    const float* b2    = (const float*)d_in[6];
    const float* Wh    = (const float*)d_in[7];
    const float* bh    = (const float*)d_in[8];
    float* out = (float*)d_out;
    const int* src = ei;
    const int* dst = ei + N_EDGES;

    char* ws = (char*)d_ws;
    size_t off = 0;
    auto alloc = [&](size_t bytes) {
        void* p = ws + off;
        off += (bytes + 255) & ~(size_t)255;
        return p;
    };
    u16*   bufA   = (u16*) alloc((size_t)N_NODES * DIM * 2);        // 12.8 MB bf16
    u16*   bufB   = (u16*) alloc((size_t)N_NODES * DIM * 2);        // 12.8 MB bf16
    int*   cnt    = (int*) alloc((size_t)N_NODES * 4);              // 200 KB packed
    int*   bucket = (int*) alloc((size_t)N_NODES * CAP * 4);        // 12.8 MB
    u16*   W1s    = (u16*) alloc((size_t)DIM * DIM * 2);
    u16*   W2s    = (u16*) alloc((size_t)DIM * DIM * 2);
    float* pooled = (float*)alloc((size_t)NGRAPH * DIM * 4);
    (void)ws_size; (void)in_sizes; (void)n_in; (void)out_size;

    k_prep    <<<G_PREP, 256, 0, stream>>>(W1, W2, W1s, W2s, pooled, cnt);
    k_front   <<<G_FRONT, 256, 0, stream>>>(x, src, dst, cnt, bucket, W1s, bufA);
    k_agg_gemm<<<N_NODES / 16, 256, 0, stream>>>(bufA, bucket, cnt, b1, W2s, bufB);
    k_agg_pool<<<N_NODES / 16, 256, 0, stream>>>(bufB, bucket, cnt, b2, batch, pooled);

    k_head<<<NGRAPH, 64, 0, stream>>>(pooled, Wh, bh, out);
}